// Round 1
// baseline (40.197 us; speedup 1.0000x reference)
//
#include <hip/hip_runtime.h>

// Problem constants (fixed by setup_inputs: x = [8, 4096, 512] float32)
#define BB 8
#define TT 4096
#define CC 512
#define C4 (CC / 4)        // 128 float4 per row
#define CHUNK 32           // t-steps per block
#define NCHUNK (TT / CHUNK) // 128 chunks
#define LOG2_NCHUNK 7

// ---------------------------------------------------------------------------
// Kernel 1: per-chunk partial sums.
// Block = 128 threads, one thread per float4 column (4 channels).
// Grid = BB * NCHUNK blocks. Each thread sums CHUNK rows of its column and
// writes one float4 to ws[b][chunk][c4].
// ---------------------------------------------------------------------------
__global__ __launch_bounds__(128) void cbow_chunksum(
    const float4* __restrict__ in4, float4* __restrict__ ws4) {
    const int blk   = blockIdx.x;
    const int b     = blk >> LOG2_NCHUNK;
    const int chunk = blk & (NCHUNK - 1);
    const int c4    = threadIdx.x;

    size_t base = ((size_t)b * TT + (size_t)chunk * CHUNK) * C4 + c4;

    float4 acc = make_float4(0.f, 0.f, 0.f, 0.f);
#pragma unroll 8
    for (int t = 0; t < CHUNK; ++t) {
        float4 v = in4[base + (size_t)t * C4];
        acc.x += v.x; acc.y += v.y; acc.z += v.z; acc.w += v.w;
    }
    ws4[((size_t)b * NCHUNK + chunk) * C4 + c4] = acc;
}

// ---------------------------------------------------------------------------
// Kernel 2: exclusive chunk-prefix (from the small ws table, L2-resident,
// independent coalesced loads -> latency hidden by ILP) + local scan + scale.
// ---------------------------------------------------------------------------
__global__ __launch_bounds__(128) void cbow_scan(
    const float4* __restrict__ in4, const float4* __restrict__ ws4,
    float4* __restrict__ out4) {
    const int blk   = blockIdx.x;
    const int b     = blk >> LOG2_NCHUNK;
    const int chunk = blk & (NCHUNK - 1);
    const int c4    = threadIdx.x;

    // Exclusive prefix over predecessor chunk sums (0..chunk-1 iterations).
    float4 acc = make_float4(0.f, 0.f, 0.f, 0.f);
    size_t wbase = (size_t)b * NCHUNK * C4 + c4;
#pragma unroll 4
    for (int k = 0; k < chunk; ++k) {
        float4 v = ws4[wbase + (size_t)k * C4];
        acc.x += v.x; acc.y += v.y; acc.z += v.z; acc.w += v.w;
    }

    // Local scan over this chunk's CHUNK rows, scale by 1/(t+1), store.
    size_t base = ((size_t)b * TT + (size_t)chunk * CHUNK) * C4 + c4;
#pragma unroll 8
    for (int t = 0; t < CHUNK; ++t) {
        float4 v = in4[base + (size_t)t * C4];
        acc.x += v.x; acc.y += v.y; acc.z += v.z; acc.w += v.w;
        const float inv = 1.0f / (float)(chunk * CHUNK + t + 1);
        float4 o;
        o.x = acc.x * inv; o.y = acc.y * inv;
        o.z = acc.z * inv; o.w = acc.w * inv;
        out4[base + (size_t)t * C4] = o;
    }
}

extern "C" void kernel_launch(void* const* d_in, const int* in_sizes, int n_in,
                              void* d_out, int out_size, void* d_ws, size_t ws_size,
                              hipStream_t stream) {
    const float4* in4  = (const float4*)d_in[0];
    float4*       out4 = (float4*)d_out;
    float4*       ws4  = (float4*)d_ws;  // needs BB*NCHUNK*CC*4 = 2 MiB

    dim3 grid(BB * NCHUNK);
    dim3 block(128);
    cbow_chunksum<<<grid, block, 0, stream>>>(in4, ws4);
    cbow_scan<<<grid, block, 0, stream>>>(in4, ws4, out4);
}